// Round 1
// baseline (326.099 us; speedup 1.0000x reference)
//
#include <hip/hip_runtime.h>
#include <hip/hip_bf16.h>

typedef __attribute__((ext_vector_type(8))) short short8;
typedef __attribute__((ext_vector_type(4))) short short4v;
typedef __attribute__((ext_vector_type(4))) float f32x4;

#define MFMA16(a, b, c) __builtin_amdgcn_mfma_f32_16x16x32_bf16((a), (b), (c), 0, 0, 0)

__device__ __forceinline__ short f2bf(float f) {
    union { __hip_bfloat16 h; short s; } u;
    u.h = __float2bfloat16(f);
    return u.s;
}

// ---------------- K0: fp32 -> bf16 weight convert ----------------
__global__ __launch_bounds__(256) void wconv_kernel(
    const float* __restrict__ wq, const float* __restrict__ wkv, const float* __restrict__ wo,
    short* __restrict__ wq_bf, short* __restrict__ wkv_bf, short* __restrict__ wo_bf) {
    int i = blockIdx.x * 256 + threadIdx.x;
    if (i < 512 * 128) wq_bf[i] = f2bf(wq[i]);
    if (i < 1024 * 128) wkv_bf[i] = f2bf(wkv[i]);
    if (i < 128 * 512) wo_bf[i] = f2bf(wo[i]);
}

// ---------------- K1: depthwise 3x3x3 stride1 pad1 + BN -> qd_t[b][i][c] bf16 ----------------
__global__ __launch_bounds__(256) void dwq_kernel(
    const float* __restrict__ x, const float* __restrict__ w,
    const float* __restrict__ gg, const float* __restrict__ bb,
    const float* __restrict__ mm, const float* __restrict__ vv,
    short* __restrict__ qd_t) {
    __shared__ float xs[64][9][17];
    const int by = blockIdx.x, bz = blockIdx.y, b = blockIdx.z;
    const int tid = threadIdx.x;
    const int xx = tid & 15, cg = tid >> 4;  // cg 0..15
    const int i = (bz * 16 + by) * 16 + xx;
    #pragma unroll
    for (int half = 0; half < 2; ++half) {
        if (half) __syncthreads();
        for (int k = 0; k < 36; ++k) {
            int idx = k * 256 + tid;
            int cl = idx / 144, rem = idx % 144;
            int row = rem >> 4, lx = idx & 15;
            int dz = row / 3, dy = row - dz * 3;
            int iz = bz + dz - 1, iy = by + dy - 1;
            float val = 0.f;
            if ((unsigned)iz < 16u && (unsigned)iy < 16u)
                val = x[(((b * 128 + half * 64 + cl) * 16 + iz) * 16 + iy) * 16 + lx];
            xs[cl][row][lx] = val;
        }
        __syncthreads();
        short4v outv;
        #pragma unroll
        for (int cc = 0; cc < 4; ++cc) {
            int cl = cg * 4 + cc;
            int c = half * 64 + cl;
            const float* wc = w + c * 27;
            float s = 0.f;
            #pragma unroll
            for (int row = 0; row < 9; ++row) {
                if (xx > 0) s += xs[cl][row][xx - 1] * wc[row * 3 + 0];
                s += xs[cl][row][xx] * wc[row * 3 + 1];
                if (xx < 15) s += xs[cl][row][xx + 1] * wc[row * 3 + 2];
            }
            float sc = gg[c] * rsqrtf(vv[c] + 1e-5f);
            float sh = bb[c] - mm[c] * sc;
            outv[cc] = f2bf(s * sc + sh);
        }
        *(short4v*)(qd_t + ((long)b * 4096 + i) * 128 + half * 64 + cg * 4) = outv;
    }
}

// ---------------- K2: depthwise 3x3x3 stride2 pad1 + BN -> kvd_t[b][j][c] bf16 ----------------
__global__ __launch_bounds__(128) void dwkv_kernel(
    const float* __restrict__ x, const float* __restrict__ w,
    const float* __restrict__ gg, const float* __restrict__ bb,
    const float* __restrict__ mm, const float* __restrict__ vv,
    short* __restrict__ kvd_t) {
    __shared__ float xs[64][9][17];
    const int oy = blockIdx.x, oz = blockIdx.y, b = blockIdx.z;
    const int tid = threadIdx.x;
    const int ox = tid & 7, cg = tid >> 3;  // cg 0..15
    const int j = (oz * 8 + oy) * 8 + ox;
    #pragma unroll
    for (int half = 0; half < 2; ++half) {
        if (half) __syncthreads();
        for (int k = 0; k < 72; ++k) {
            int idx = k * 128 + tid;
            int cl = idx / 144, rem = idx % 144;
            int row = rem >> 4, lx = idx & 15;
            int dz = row / 3, dy = row - dz * 3;
            int iz = 2 * oz + dz - 1, iy = 2 * oy + dy - 1;
            float val = 0.f;
            if ((unsigned)iz < 16u && (unsigned)iy < 16u)
                val = x[(((b * 128 + half * 64 + cl) * 16 + iz) * 16 + iy) * 16 + lx];
            xs[cl][row][lx] = val;
        }
        __syncthreads();
        short4v outv;
        #pragma unroll
        for (int cc = 0; cc < 4; ++cc) {
            int cl = cg * 4 + cc;
            int c = half * 64 + cl;
            const float* wc = w + c * 27;
            float s = 0.f;
            #pragma unroll
            for (int row = 0; row < 9; ++row) {
                #pragma unroll
                for (int dx = 0; dx < 3; ++dx) {
                    int ix = 2 * ox + dx - 1;
                    if ((unsigned)ix < 16u) s += xs[cl][row][ix] * wc[row * 3 + dx];
                }
            }
            float sc = gg[c] * rsqrtf(vv[c] + 1e-5f);
            float sh = bb[c] - mm[c] * sc;
            outv[cc] = f2bf(s * sc + sh);
        }
        *(short4v*)(kvd_t + ((long)b * 512 + j) * 128 + half * 64 + cg * 4) = outv;
    }
}

// ---------------- K3: pointwise q GEMM: q_t[b][h][i][d] = Wq(512x128) x qd_t^T ----------------
__global__ __launch_bounds__(256) void pwq_kernel(
    const short* __restrict__ wq_bf, const short* __restrict__ qd_t, short* __restrict__ q_t) {
    const int bi = blockIdx.x, bo = blockIdx.y, b = blockIdx.z;
    const int tid = threadIdx.x, lane = tid & 63, wv = tid >> 6;
    const int jl = lane & 15, gq = lane >> 4;
    const int wm = wv >> 1, wn = wv & 1;
    const int o0 = bo * 128 + wm * 64, i0 = bi * 128 + wn * 64;
    short8 A[4][4];
    #pragma unroll
    for (int m = 0; m < 4; ++m)
        #pragma unroll
        for (int ks = 0; ks < 4; ++ks)
            A[m][ks] = *(const short8*)(wq_bf + (o0 + m * 16 + jl) * 128 + ks * 32 + gq * 8);
    f32x4 acc[4][4];
    #pragma unroll
    for (int m = 0; m < 4; ++m)
        #pragma unroll
        for (int n = 0; n < 4; ++n) acc[m][n] = (f32x4){0.f, 0.f, 0.f, 0.f};
    const short* Bb = qd_t + (long)b * 4096 * 128;
    #pragma unroll
    for (int ks = 0; ks < 4; ++ks)
        #pragma unroll
        for (int n = 0; n < 4; ++n) {
            short8 Bf = *(const short8*)(Bb + (i0 + n * 16 + jl) * 128 + ks * 32 + gq * 8);
            #pragma unroll
            for (int m = 0; m < 4; ++m) acc[m][n] = MFMA16(A[m][ks], Bf, acc[m][n]);
        }
    const int h = bo * 2 + wm;
    short* qo = q_t + ((long)(b * 8 + h)) * 4096 * 64;
    #pragma unroll
    for (int m = 0; m < 4; ++m) {
        int ddb = m * 16 + gq * 4;
        #pragma unroll
        for (int n = 0; n < 4; ++n) {
            int ii = i0 + n * 16 + jl;
            short4v pk;
            #pragma unroll
            for (int r = 0; r < 4; ++r) pk[r] = f2bf(acc[m][n][r]);
            *(short4v*)(qo + (long)ii * 64 + ddb) = pk;
        }
    }
}

// ---------------- K4: pointwise kv GEMM -> k_t[b][h][j][d], v[b][h][d][j] ----------------
__global__ __launch_bounds__(256) void pwkv_kernel(
    const short* __restrict__ wkv_bf, const short* __restrict__ kvd_t,
    short* __restrict__ k_t, short* __restrict__ v_t) {
    const int bj = blockIdx.x, bo = blockIdx.y, b = blockIdx.z;
    const int tid = threadIdx.x, lane = tid & 63, wv = tid >> 6;
    const int jl = lane & 15, gq = lane >> 4;
    const int wm = wv >> 1, wn = wv & 1;
    const int o0 = bo * 128 + wm * 64, j0 = bj * 128 + wn * 64;
    short8 A[4][4];
    #pragma unroll
    for (int m = 0; m < 4; ++m)
        #pragma unroll
        for (int ks = 0; ks < 4; ++ks)
            A[m][ks] = *(const short8*)(wkv_bf + (o0 + m * 16 + jl) * 128 + ks * 32 + gq * 8);
    f32x4 acc[4][4];
    #pragma unroll
    for (int m = 0; m < 4; ++m)
        #pragma unroll
        for (int n = 0; n < 4; ++n) acc[m][n] = (f32x4){0.f, 0.f, 0.f, 0.f};
    const short* Bb = kvd_t + (long)b * 512 * 128;
    #pragma unroll
    for (int ks = 0; ks < 4; ++ks)
        #pragma unroll
        for (int n = 0; n < 4; ++n) {
            short8 Bf = *(const short8*)(Bb + (j0 + n * 16 + jl) * 128 + ks * 32 + gq * 8);
            #pragma unroll
            for (int m = 0; m < 4; ++m) acc[m][n] = MFMA16(A[m][ks], Bf, acc[m][n]);
        }
    const int hh = bo * 2 + wm;  // 0..15: <8 -> K half, >=8 -> V half
    if (hh < 8) {
        short* ko = k_t + ((long)(b * 8 + hh)) * 512 * 64;
        #pragma unroll
        for (int m = 0; m < 4; ++m) {
            int ddb = m * 16 + gq * 4;
            #pragma unroll
            for (int n = 0; n < 4; ++n) {
                int jj = j0 + n * 16 + jl;
                short4v pk;
                #pragma unroll
                for (int r = 0; r < 4; ++r) pk[r] = f2bf(acc[m][n][r]);
                *(short4v*)(ko + (long)jj * 64 + ddb) = pk;
            }
        }
    } else {
        short* vo = v_t + ((long)(b * 8 + hh - 8)) * 64 * 512;
        #pragma unroll
        for (int m = 0; m < 4; ++m)
            #pragma unroll
            for (int n = 0; n < 4; ++n) {
                int jj = j0 + n * 16 + jl;
                #pragma unroll
                for (int r = 0; r < 4; ++r)
                    vo[(long)(m * 16 + gq * 4 + r) * 512 + jj] = f2bf(acc[m][n][r]);
            }
    }
}

// ---------------- K5: attention (32 q-rows/block, full 512-wide softmax) ----------------
__global__ __launch_bounds__(256) void attn_kernel(
    const short* __restrict__ q_t, const short* __restrict__ k_t,
    const short* __restrict__ v_t, short* __restrict__ attn_t) {
    __shared__ short P[32][520];  // padded rows: 520*2B = 1040B -> conflict-benign
    __shared__ float smax[4][32];
    __shared__ float ssum[4][32];
    const int qt = blockIdx.x, h = blockIdx.y, b = blockIdx.z;
    const int tid = threadIdx.x, lane = tid & 63, wv = tid >> 6;
    const int jl = lane & 15, gq = lane >> 4;
    const int i0 = qt * 32;
    const short* qp = q_t + ((long)(b * 8 + h)) * 4096 * 64;
    const short* kp = k_t + ((long)(b * 8 + h)) * 512 * 64;
    const short* vp = v_t + ((long)(b * 8 + h)) * 64 * 512;

    short8 QA[2][2];
    #pragma unroll
    for (int m = 0; m < 2; ++m)
        #pragma unroll
        for (int ks = 0; ks < 2; ++ks)
            QA[m][ks] = *(const short8*)(qp + (i0 + m * 16 + jl) * 64 + ks * 32 + gq * 8);

    f32x4 S[2][8];
    #pragma unroll
    for (int m = 0; m < 2; ++m)
        #pragma unroll
        for (int n = 0; n < 8; ++n) S[m][n] = (f32x4){0.f, 0.f, 0.f, 0.f};

    #pragma unroll
    for (int n = 0; n < 8; ++n) {
        int j0 = wv * 128 + n * 16;
        #pragma unroll
        for (int ks = 0; ks < 2; ++ks) {
            short8 KB = *(const short8*)(kp + (j0 + jl) * 64 + ks * 32 + gq * 8);
            S[0][n] = MFMA16(QA[0][ks], KB, S[0][n]);
            S[1][n] = MFMA16(QA[1][ks], KB, S[1][n]);
        }
    }
    // wave-partial row max over this wave's 128 j's
    #pragma unroll
    for (int m = 0; m < 2; ++m)
        #pragma unroll
        for (int r = 0; r < 4; ++r) {
            float v = S[m][0][r];
            #pragma unroll
            for (int n = 1; n < 8; ++n) v = fmaxf(v, S[m][n][r]);
            #pragma unroll
            for (int msk = 1; msk < 16; msk <<= 1) v = fmaxf(v, __shfl_xor(v, msk, 64));
            if (jl == 0) smax[wv][m * 16 + gq * 4 + r] = v;
        }
    __syncthreads();
    float rmax[2][4], ps[2][4];
    #pragma unroll
    for (int m = 0; m < 2; ++m)
        #pragma unroll
        for (int r = 0; r < 4; ++r) {
            int il = m * 16 + gq * 4 + r;
            rmax[m][r] = fmaxf(fmaxf(smax[0][il], smax[1][il]), fmaxf(smax[2][il], smax[3][il]));
            ps[m][r] = 0.f;
        }
    #pragma unroll
    for (int m = 0; m < 2; ++m)
        #pragma unroll
        for (int n = 0; n < 8; ++n) {
            int jj = wv * 128 + n * 16 + jl;
            #pragma unroll
            for (int r = 0; r < 4; ++r) {
                float p = __expf((S[m][n][r] - rmax[m][r]) * 0.125f);
                ps[m][r] += p;
                P[m * 16 + gq * 4 + r][jj] = f2bf(p);
            }
        }
    #pragma unroll
    for (int m = 0; m < 2; ++m)
        #pragma unroll
        for (int r = 0; r < 4; ++r) {
            float v = ps[m][r];
            #pragma unroll
            for (int msk = 1; msk < 16; msk <<= 1) v += __shfl_xor(v, msk, 64);
            if (jl == 0) ssum[wv][m * 16 + gq * 4 + r] = v;
        }
    __syncthreads();
    float inv[2][4];
    #pragma unroll
    for (int m = 0; m < 2; ++m)
        #pragma unroll
        for (int r = 0; r < 4; ++r) {
            int il = m * 16 + gq * 4 + r;
            inv[m][r] = 1.f / (ssum[0][il] + ssum[1][il] + ssum[2][il] + ssum[3][il]);
        }
    f32x4 O[2];
    O[0] = (f32x4){0.f, 0.f, 0.f, 0.f};
    O[1] = (f32x4){0.f, 0.f, 0.f, 0.f};
    #pragma unroll
    for (int ks = 0; ks < 16; ++ks) {
        short8 VB = *(const short8*)(vp + (wv * 16 + jl) * 512 + ks * 32 + gq * 8);
        short8 PA0 = *(const short8*)(&P[jl][ks * 32 + gq * 8]);
        short8 PA1 = *(const short8*)(&P[16 + jl][ks * 32 + gq * 8]);
        O[0] = MFMA16(PA0, VB, O[0]);
        O[1] = MFMA16(PA1, VB, O[1]);
    }
    short* op = attn_t + (long)b * 4096 * 512 + h * 64 + wv * 16 + jl;
    #pragma unroll
    for (int m = 0; m < 2; ++m)
        #pragma unroll
        for (int r = 0; r < 4; ++r) {
            int ii = i0 + m * 16 + gq * 4 + r;
            op[(long)ii * 512] = f2bf(O[m][r] * inv[m][r]);
        }
}

// ---------------- K6: out GEMM + bias -> fp32 d_out ----------------
__global__ __launch_bounds__(256) void out_kernel(
    const short* __restrict__ wo_bf, const short* __restrict__ attn_t,
    const float* __restrict__ bias, float* __restrict__ out) {
    const int bi = blockIdx.x, b = blockIdx.z;
    const int tid = threadIdx.x, lane = tid & 63, wv = tid >> 6;
    const int jl = lane & 15, gq = lane >> 4;
    const int wm = wv >> 1, wn = wv & 1;
    const int o0 = wm * 64, i0 = bi * 128 + wn * 64;
    f32x4 acc[4][4];
    #pragma unroll
    for (int m = 0; m < 4; ++m)
        #pragma unroll
        for (int n = 0; n < 4; ++n) acc[m][n] = (f32x4){0.f, 0.f, 0.f, 0.f};
    const short* Bb = attn_t + (long)b * 4096 * 512;
    #pragma unroll 2
    for (int ks = 0; ks < 16; ++ks) {
        short8 A[4];
        #pragma unroll
        for (int m = 0; m < 4; ++m)
            A[m] = *(const short8*)(wo_bf + (o0 + m * 16 + jl) * 512 + ks * 32 + gq * 8);
        #pragma unroll
        for (int n = 0; n < 4; ++n) {
            short8 Bf = *(const short8*)(Bb + (long)(i0 + n * 16 + jl) * 512 + ks * 32 + gq * 8);
            #pragma unroll
            for (int m = 0; m < 4; ++m) acc[m][n] = MFMA16(A[m], Bf, acc[m][n]);
        }
    }
    #pragma unroll
    for (int m = 0; m < 4; ++m)
        #pragma unroll
        for (int n = 0; n < 4; ++n) {
            int ii = i0 + n * 16 + jl;
            #pragma unroll
            for (int r = 0; r < 4; ++r) {
                int co = o0 + m * 16 + gq * 4 + r;
                out[((long)(b * 128 + co)) * 4096 + ii] = acc[m][n][r] + bias[co];
            }
        }
}

extern "C" void kernel_launch(void* const* d_in, const int* in_sizes, int n_in,
                              void* d_out, int out_size, void* d_ws, size_t ws_size,
                              hipStream_t stream) {
    const float* x      = (const float*)d_in[0];
    const float* wq_dw  = (const float*)d_in[1];
    const float* bnq_g  = (const float*)d_in[2];
    const float* bnq_b  = (const float*)d_in[3];
    const float* bnq_m  = (const float*)d_in[4];
    const float* bnq_v  = (const float*)d_in[5];
    const float* wq_pw  = (const float*)d_in[6];
    const float* wkv_dw = (const float*)d_in[7];
    const float* bnk_g  = (const float*)d_in[8];
    const float* bnk_b  = (const float*)d_in[9];
    const float* bnk_m  = (const float*)d_in[10];
    const float* bnk_v  = (const float*)d_in[11];
    const float* wkv_pw = (const float*)d_in[12];
    const float* w_out  = (const float*)d_in[13];
    const float* b_out  = (const float*)d_in[14];
    float* out = (float*)d_out;

    char* ws = (char*)d_ws;
    // workspace layout (bytes), total ~41 MB
    short* wq_bf  = (short*)(ws + 0);          //  512*128*2 = 131072
    short* wkv_bf = (short*)(ws + 131072);     // 1024*128*2 = 262144
    short* wo_bf  = (short*)(ws + 393216);     //  128*512*2 = 131072
    short* qd_t   = (short*)(ws + 524288);     // 4*4096*128*2 = 4194304
    short* kvd_t  = (short*)(ws + 4718592);    // 4*512*128*2 = 524288
    short* q_t    = (short*)(ws + 5242880);    // 4*8*4096*64*2 = 16777216
    short* k_t    = (short*)(ws + 22020096);   // 4*8*512*64*2 = 2097152
    short* v_t    = (short*)(ws + 24117248);   // 4*8*64*512*2 = 2097152
    short* attn_t = (short*)(ws + 26214400);   // 4*4096*512*2 = 16777216

    wconv_kernel<<<dim3(512), dim3(256), 0, stream>>>(wq_pw, wkv_pw, w_out, wq_bf, wkv_bf, wo_bf);
    dwq_kernel<<<dim3(16, 16, 4), dim3(256), 0, stream>>>(x, wq_dw, bnq_g, bnq_b, bnq_m, bnq_v, qd_t);
    dwkv_kernel<<<dim3(8, 8, 4), dim3(128), 0, stream>>>(x, wkv_dw, bnk_g, bnk_b, bnk_m, bnk_v, kvd_t);
    pwq_kernel<<<dim3(32, 4, 4), dim3(256), 0, stream>>>(wq_bf, qd_t, q_t);
    pwkv_kernel<<<dim3(4, 8, 4), dim3(256), 0, stream>>>(wkv_bf, kvd_t, k_t, v_t);
    attn_kernel<<<dim3(128, 8, 4), dim3(256), 0, stream>>>(q_t, k_t, v_t, attn_t);
    out_kernel<<<dim3(32, 1, 4), dim3(256), 0, stream>>>(wo_bf, attn_t, b_out, out);
}

// Round 2
// 211.849 us; speedup vs baseline: 1.5393x; 1.5393x over previous
//
#include <hip/hip_runtime.h>
#include <hip/hip_bf16.h>

typedef __attribute__((ext_vector_type(8))) short short8;
typedef __attribute__((ext_vector_type(4))) short short4v;
typedef __attribute__((ext_vector_type(4))) float f32x4;

#define MFMA16(a, b, c) __builtin_amdgcn_mfma_f32_16x16x32_bf16((a), (b), (c), 0, 0, 0)

__device__ __forceinline__ short f2bf(float f) {
    union { __hip_bfloat16 h; short s; } u;
    u.h = __float2bfloat16(f);
    return u.s;
}

__device__ __forceinline__ unsigned pk2(float lo, float hi) {
    unsigned a = (unsigned short)f2bf(lo);
    unsigned b = (unsigned short)f2bf(hi);
    return a | (b << 16);
}

// ---------------- K0: fp32 -> bf16 weight convert ----------------
__global__ __launch_bounds__(256) void wconv_kernel(
    const float* __restrict__ wq, const float* __restrict__ wkv, const float* __restrict__ wo,
    short* __restrict__ wq_bf, short* __restrict__ wkv_bf, short* __restrict__ wo_bf) {
    int i = blockIdx.x * 256 + threadIdx.x;
    if (i < 512 * 128) wq_bf[i] = f2bf(wq[i]);
    if (i < 1024 * 128) wkv_bf[i] = f2bf(wkv[i]);
    if (i < 128 * 512) wo_bf[i] = f2bf(wo[i]);
}

// ---------------- K1: depthwise 3x3x3 s1 p1 + BN -> qd_t[b][i][c] bf16 ----------------
// block: (c-group of 16) x (one z slice) ; 256 threads = 16x16 (y,x) positions
__global__ __launch_bounds__(256) void dwq_kernel(
    const float* __restrict__ x, const float* __restrict__ w,
    const float* __restrict__ gg, const float* __restrict__ bb,
    const float* __restrict__ mm, const float* __restrict__ vv,
    short* __restrict__ qd_t) {
    __shared__ float xs[16][3][16][17];
    const int cg = blockIdx.x, z = blockIdx.y, b = blockIdx.z;
    const int tid = threadIdx.x;
    const int y = tid >> 4, xx = tid & 15;
    const int c0 = cg * 16;
    // stage 3 z-planes for 16 channels (each iter: one full 16x16 plane, coalesced)
    #pragma unroll 4
    for (int ch = 0; ch < 16; ++ch)
        for (int zz = 0; zz < 3; ++zz) {
            int iz = z + zz - 1;
            float val = 0.f;
            if ((unsigned)iz < 16u)
                val = x[(((b * 128 + c0 + ch) * 16 + iz) * 16 + y) * 16 + xx];
            xs[ch][zz][y][xx] = val;
        }
    __syncthreads();
    short res[16];
    #pragma unroll
    for (int ch = 0; ch < 16; ++ch) {
        const int c = c0 + ch;
        const float* wc = w + c * 27;
        float s = 0.f;
        #pragma unroll
        for (int zz = 0; zz < 3; ++zz)
            #pragma unroll
            for (int dy = 0; dy < 3; ++dy) {
                int iy = y + dy - 1;
                if ((unsigned)iy < 16u) {
                    float v  = xs[ch][zz][iy][xx];
                    float vm = __shfl_up(v, 1, 16);
                    float vp = __shfl_down(v, 1, 16);
                    float w0 = wc[zz * 9 + dy * 3 + 0];
                    float w1 = wc[zz * 9 + dy * 3 + 1];
                    float w2 = wc[zz * 9 + dy * 3 + 2];
                    if (xx > 0)  s += vm * w0;
                    s += v * w1;
                    if (xx < 15) s += vp * w2;
                }
            }
        float sc = gg[c] * rsqrtf(vv[c] + 1e-5f);
        float sh = bb[c] - mm[c] * sc;
        res[ch] = f2bf(s * sc + sh);
    }
    const int i = z * 256 + tid;
    short8 o0, o1;
    #pragma unroll
    for (int k = 0; k < 8; ++k) { o0[k] = res[k]; o1[k] = res[8 + k]; }
    short* dst = qd_t + ((long)b * 4096 + i) * 128 + c0;
    *(short8*)dst = o0;
    *(short8*)(dst + 8) = o1;
}

// ---------------- K2: depthwise 3x3x3 s2 p1 + BN -> kvd_t[b][j][c] bf16 ----------------
// block: (c-group of 16) x (one output-z slice); 256 threads = 64 pos x 4 c-quads
__global__ __launch_bounds__(256) void dwkv_kernel(
    const float* __restrict__ x, const float* __restrict__ w,
    const float* __restrict__ gg, const float* __restrict__ bb,
    const float* __restrict__ mm, const float* __restrict__ vv,
    short* __restrict__ kvd_t) {
    __shared__ float xs[16][3][16][17];
    const int cg = blockIdx.x, oz = blockIdx.y, b = blockIdx.z;
    const int tid = threadIdx.x;
    const int y = tid >> 4, xx = tid & 15;
    const int c0 = cg * 16;
    #pragma unroll 4
    for (int ch = 0; ch < 16; ++ch)
        for (int zz = 0; zz < 3; ++zz) {
            int iz = 2 * oz + zz - 1;
            float val = 0.f;
            if ((unsigned)iz < 16u)
                val = x[(((b * 128 + c0 + ch) * 16 + iz) * 16 + y) * 16 + xx];
            xs[ch][zz][y][xx] = val;
        }
    __syncthreads();
    const int pos = tid & 63, cq = tid >> 6;
    const int oy = pos >> 3, ox = pos & 7;
    short4v outv;
    #pragma unroll
    for (int cc = 0; cc < 4; ++cc) {
        const int chl = cq * 4 + cc;
        const int c = c0 + chl;
        const float* wc = w + c * 27;
        float s = 0.f;
        #pragma unroll
        for (int zz = 0; zz < 3; ++zz)
            #pragma unroll
            for (int dy = 0; dy < 3; ++dy) {
                int iy = 2 * oy + dy - 1;
                if ((unsigned)iy < 16u) {
                    #pragma unroll
                    for (int dx = 0; dx < 3; ++dx) {
                        int ix = 2 * ox + dx - 1;
                        if ((unsigned)ix < 16u)
                            s += xs[chl][zz][iy][ix] * wc[zz * 9 + dy * 3 + dx];
                    }
                }
            }
        float sc = gg[c] * rsqrtf(vv[c] + 1e-5f);
        float sh = bb[c] - mm[c] * sc;
        outv[cc] = f2bf(s * sc + sh);
    }
    const int j = oz * 64 + pos;
    *(short4v*)(kvd_t + ((long)b * 512 + j) * 128 + c0 + cq * 4) = outv;
}

// ---------------- K3: pointwise q GEMM: q_t[b][h][i][d] ----------------
__global__ __launch_bounds__(256) void pwq_kernel(
    const short* __restrict__ wq_bf, const short* __restrict__ qd_t, short* __restrict__ q_t) {
    const int bi = blockIdx.x, bo = blockIdx.y, b = blockIdx.z;
    const int tid = threadIdx.x, lane = tid & 63, wv = tid >> 6;
    const int jl = lane & 15, gq = lane >> 4;
    const int wm = wv >> 1, wn = wv & 1;
    const int o0 = bo * 128 + wm * 64, i0 = bi * 128 + wn * 64;
    short8 A[4][4];
    #pragma unroll
    for (int m = 0; m < 4; ++m)
        #pragma unroll
        for (int ks = 0; ks < 4; ++ks)
            A[m][ks] = *(const short8*)(wq_bf + (o0 + m * 16 + jl) * 128 + ks * 32 + gq * 8);
    f32x4 acc[4][4];
    #pragma unroll
    for (int m = 0; m < 4; ++m)
        #pragma unroll
        for (int n = 0; n < 4; ++n) acc[m][n] = (f32x4){0.f, 0.f, 0.f, 0.f};
    const short* Bb = qd_t + (long)b * 4096 * 128;
    #pragma unroll
    for (int ks = 0; ks < 4; ++ks)
        #pragma unroll
        for (int n = 0; n < 4; ++n) {
            short8 Bf = *(const short8*)(Bb + (i0 + n * 16 + jl) * 128 + ks * 32 + gq * 8);
            #pragma unroll
            for (int m = 0; m < 4; ++m) acc[m][n] = MFMA16(A[m][ks], Bf, acc[m][n]);
        }
    const int h = bo * 2 + wm;
    short* qo = q_t + ((long)(b * 8 + h)) * 4096 * 64;
    #pragma unroll
    for (int m = 0; m < 4; ++m) {
        int ddb = m * 16 + gq * 4;
        #pragma unroll
        for (int n = 0; n < 4; ++n) {
            int ii = i0 + n * 16 + jl;
            short4v pk;
            #pragma unroll
            for (int r = 0; r < 4; ++r) pk[r] = f2bf(acc[m][n][r]);
            *(short4v*)(qo + (long)ii * 64 + ddb) = pk;
        }
    }
}

// ---------------- K4: pointwise kv GEMM -> k_t[b][h][j][d], v_t[b][h][d][j] ----------------
__global__ __launch_bounds__(256) void pwkv_kernel(
    const short* __restrict__ wkv_bf, const short* __restrict__ kvd_t,
    short* __restrict__ k_t, short* __restrict__ v_t) {
    const int bj = blockIdx.x, bo = blockIdx.y, b = blockIdx.z;
    const int tid = threadIdx.x, lane = tid & 63, wv = tid >> 6;
    const int jl = lane & 15, gq = lane >> 4;
    const int wm = wv >> 1, wn = wv & 1;
    const int o0 = bo * 128 + wm * 64, j0 = bj * 128 + wn * 64;
    short8 A[4][4];
    #pragma unroll
    for (int m = 0; m < 4; ++m)
        #pragma unroll
        for (int ks = 0; ks < 4; ++ks)
            A[m][ks] = *(const short8*)(wkv_bf + (o0 + m * 16 + jl) * 128 + ks * 32 + gq * 8);
    f32x4 acc[4][4];
    #pragma unroll
    for (int m = 0; m < 4; ++m)
        #pragma unroll
        for (int n = 0; n < 4; ++n) acc[m][n] = (f32x4){0.f, 0.f, 0.f, 0.f};
    const short* Bb = kvd_t + (long)b * 512 * 128;
    #pragma unroll
    for (int ks = 0; ks < 4; ++ks)
        #pragma unroll
        for (int n = 0; n < 4; ++n) {
            short8 Bf = *(const short8*)(Bb + (j0 + n * 16 + jl) * 128 + ks * 32 + gq * 8);
            #pragma unroll
            for (int m = 0; m < 4; ++m) acc[m][n] = MFMA16(A[m][ks], Bf, acc[m][n]);
        }
    const int hh = bo * 2 + wm;
    if (hh < 8) {
        short* ko = k_t + ((long)(b * 8 + hh)) * 512 * 64;
        #pragma unroll
        for (int m = 0; m < 4; ++m) {
            int ddb = m * 16 + gq * 4;
            #pragma unroll
            for (int n = 0; n < 4; ++n) {
                int jj = j0 + n * 16 + jl;
                short4v pk;
                #pragma unroll
                for (int r = 0; r < 4; ++r) pk[r] = f2bf(acc[m][n][r]);
                *(short4v*)(ko + (long)jj * 64 + ddb) = pk;
            }
        }
    } else {
        short* vo = v_t + ((long)(b * 8 + hh - 8)) * 64 * 512;
        #pragma unroll
        for (int m = 0; m < 4; ++m)
            #pragma unroll
            for (int n = 0; n < 4; ++n) {
                int jj = j0 + n * 16 + jl;
                #pragma unroll
                for (int r = 0; r < 4; ++r)
                    vo[(long)(m * 16 + gq * 4 + r) * 512 + jj] = f2bf(acc[m][n][r]);
            }
    }
}

// ---------------- K5: attention v3 ----------------
// 512 thr (8 waves), 256 q-rows/block. Swapped QK^T (mfma(K,Q)) -> lane-local
// softmax rows; PV via custom k->j permutation -> P B-fragment built in-lane.
// K/V chunk (64 j) double-buffered in padded LDS. Zero barriers for softmax.
__global__ __launch_bounds__(512) void attn_kernel(
    const short* __restrict__ q_t, const short* __restrict__ k_t,
    const short* __restrict__ v_t, short* __restrict__ attn_t) {
    __shared__ short Klds[2][64][72];  // [buf][j_local][d]   rows 144B
    __shared__ short Vlds[2][64][72];  // [buf][d][j_local]   rows 144B
    const int qt = blockIdx.x, h = blockIdx.y, b = blockIdx.z;
    const int tid = threadIdx.x, lane = tid & 63, wv = tid >> 6;
    const int jl = lane & 15, gq = lane >> 4;
    const long bh = (long)(b * 8 + h);
    const short* qp = q_t + bh * 4096 * 64;
    const short* kp = k_t + bh * 512 * 64;
    const short* vp = v_t + bh * 64 * 512;
    const int iA = qt * 256 + wv * 32;  // this wave: rows iA..iA+31 (two 16-tiles)

    short8 QF[2][2];  // [i-tile][ks]
    #pragma unroll
    for (int t = 0; t < 2; ++t)
        #pragma unroll
        for (int ks = 0; ks < 2; ++ks)
            QF[t][ks] = *(const short8*)(qp + (iA + t * 16 + jl) * 64 + ks * 32 + gq * 8);

    f32x4 O[2][4];
    #pragma unroll
    for (int t = 0; t < 2; ++t)
        #pragma unroll
        for (int m = 0; m < 4; ++m) O[t][m] = (f32x4){0.f, 0.f, 0.f, 0.f};
    float m2[2] = {-3.0e38f, -3.0e38f};
    float l[2] = {0.f, 0.f};
    const float C2 = 0.18033688011112042f;  // (1/8) * log2(e)

    const int srow = tid >> 3, scol = (tid & 7) * 8;
    short8 kst, vst;
    kst = *(const short8*)(kp + srow * 64 + scol);
    vst = *(const short8*)(vp + srow * 512 + scol);
    *(short8*)&Klds[0][srow][scol] = kst;
    *(short8*)&Vlds[0][srow][scol] = vst;

    for (int c = 0; c < 8; ++c) {
        __syncthreads();
        const int buf = c & 1;
        const bool pf = (c < 7);
        if (pf) {
            int j0n = (c + 1) * 64;
            kst = *(const short8*)(kp + (j0n + srow) * 64 + scol);
            vst = *(const short8*)(vp + srow * 512 + j0n + scol);
        }
        // QK^T: S[t][n] lane holds S[j = n*16+gq*4+r][i = iT+jl]
        f32x4 S[2][4];
        #pragma unroll
        for (int t = 0; t < 2; ++t)
            #pragma unroll
            for (int n = 0; n < 4; ++n) S[t][n] = (f32x4){0.f, 0.f, 0.f, 0.f};
        #pragma unroll
        for (int n = 0; n < 4; ++n)
            #pragma unroll
            for (int ks = 0; ks < 2; ++ks) {
                short8 Kf = *(const short8*)&Klds[buf][n * 16 + jl][ks * 32 + gq * 8];
                S[0][n] = MFMA16(Kf, QF[0][ks], S[0][n]);
                S[1][n] = MFMA16(Kf, QF[1][ks], S[1][n]);
            }
        // online softmax (lane-local row i = iT + jl)
        short8 PW[2][2];  // [i-tile][k-step]
        #pragma unroll
        for (int t = 0; t < 2; ++t) {
            float cm = S[t][0][0];
            #pragma unroll
            for (int n = 0; n < 4; ++n)
                #pragma unroll
                for (int r = 0; r < 4; ++r) cm = fmaxf(cm, S[t][n][r]);
            cm = fmaxf(cm, __shfl_xor(cm, 16, 64));
            cm = fmaxf(cm, __shfl_xor(cm, 32, 64));
            float m2new = fmaxf(m2[t], cm * C2);
            float rs = exp2f(m2[t] - m2new);
            m2[t] = m2new;
            float p[4][4];
            float psum = 0.f;
            #pragma unroll
            for (int n = 0; n < 4; ++n)
                #pragma unroll
                for (int r = 0; r < 4; ++r) {
                    p[n][r] = exp2f(fmaf(S[t][n][r], C2, -m2new));
                    psum += p[n][r];
                }
            l[t] = l[t] * rs + psum;
            #pragma unroll
            for (int m = 0; m < 4; ++m) O[t][m] *= rs;
            #pragma unroll
            for (int ks2 = 0; ks2 < 2; ++ks2) {
                union { short8 s; unsigned w[4]; } pu;
                pu.w[0] = pk2(p[2 * ks2][0], p[2 * ks2][1]);
                pu.w[1] = pk2(p[2 * ks2][2], p[2 * ks2][3]);
                pu.w[2] = pk2(p[2 * ks2 + 1][0], p[2 * ks2 + 1][1]);
                pu.w[3] = pk2(p[2 * ks2 + 1][2], p[2 * ks2 + 1][3]);
                PW[t][ks2] = pu.s;
            }
        }
        // PV: O[t][m] += V^T x P  (same k->j permutation on both operands)
        #pragma unroll
        for (int ks2 = 0; ks2 < 2; ++ks2)
            #pragma unroll
            for (int m = 0; m < 4; ++m) {
                union { short8 s; short4v h[2]; } vu;
                vu.h[0] = *(const short4v*)&Vlds[buf][m * 16 + jl][(2 * ks2) * 16 + gq * 4];
                vu.h[1] = *(const short4v*)&Vlds[buf][m * 16 + jl][(2 * ks2 + 1) * 16 + gq * 4];
                O[0][m] = MFMA16(vu.s, PW[0][ks2], O[0][m]);
                O[1][m] = MFMA16(vu.s, PW[1][ks2], O[1][m]);
            }
        if (pf) {
            const int nbuf = buf ^ 1;
            *(short8*)&Klds[nbuf][srow][scol] = kst;
            *(short8*)&Vlds[nbuf][srow][scol] = vst;
        }
    }
    // epilogue: finish row sums, normalize, packed stores
    #pragma unroll
    for (int t = 0; t < 2; ++t) {
        float lt = l[t];
        lt += __shfl_xor(lt, 16, 64);
        lt += __shfl_xor(lt, 32, 64);
        float inv = 1.f / lt;
        const long irow = (long)b * 4096 + iA + t * 16 + jl;
        #pragma unroll
        for (int m = 0; m < 4; ++m) {
            short4v pk;
            #pragma unroll
            for (int r = 0; r < 4; ++r) pk[r] = f2bf(O[t][m][r] * inv);
            *(short4v*)(attn_t + irow * 512 + h * 64 + m * 16 + gq * 4) = pk;
        }
    }
}

// ---------------- K6: out GEMM + bias -> fp32 d_out (256 blocks) ----------------
__global__ __launch_bounds__(256) void out_kernel(
    const short* __restrict__ wo_bf, const short* __restrict__ attn_t,
    const float* __restrict__ bias, float* __restrict__ out) {
    const int bi = blockIdx.x, b = blockIdx.z;
    const int tid = threadIdx.x, lane = tid & 63, wv = tid >> 6;
    const int jl = lane & 15, gq = lane >> 4;
    const int wm = wv >> 1, wn = wv & 1;
    const int o0 = wm * 64, i0 = bi * 64 + wn * 32;
    f32x4 acc[4][2];
    #pragma unroll
    for (int m = 0; m < 4; ++m)
        #pragma unroll
        for (int n = 0; n < 2; ++n) acc[m][n] = (f32x4){0.f, 0.f, 0.f, 0.f};
    const short* Bb = attn_t + (long)b * 4096 * 512;
    #pragma unroll 4
    for (int ks = 0; ks < 16; ++ks) {
        short8 A[4];
        #pragma unroll
        for (int m = 0; m < 4; ++m)
            A[m] = *(const short8*)(wo_bf + (o0 + m * 16 + jl) * 512 + ks * 32 + gq * 8);
        #pragma unroll
        for (int n = 0; n < 2; ++n) {
            short8 Bf = *(const short8*)(Bb + (long)(i0 + n * 16 + jl) * 512 + ks * 32 + gq * 8);
            #pragma unroll
            for (int m = 0; m < 4; ++m) acc[m][n] = MFMA16(A[m], Bf, acc[m][n]);
        }
    }
    #pragma unroll
    for (int m = 0; m < 4; ++m)
        #pragma unroll
        for (int n = 0; n < 2; ++n) {
            int ii = i0 + n * 16 + jl;
            #pragma unroll
            for (int r = 0; r < 4; ++r) {
                int co = o0 + m * 16 + gq * 4 + r;
                out[((long)(b * 128 + co)) * 4096 + ii] = acc[m][n][r] + bias[co];
            }
        }
}

extern "C" void kernel_launch(void* const* d_in, const int* in_sizes, int n_in,
                              void* d_out, int out_size, void* d_ws, size_t ws_size,
                              hipStream_t stream) {
    const float* x      = (const float*)d_in[0];
    const float* wq_dw  = (const float*)d_in[1];
    const float* bnq_g  = (const float*)d_in[2];
    const float* bnq_b  = (const float*)d_in[3];
    const float* bnq_m  = (const float*)d_in[4];
    const float* bnq_v  = (const float*)d_in[5];
    const float* wq_pw  = (const float*)d_in[6];
    const float* wkv_dw = (const float*)d_in[7];
    const float* bnk_g  = (const float*)d_in[8];
    const float* bnk_b  = (const float*)d_in[9];
    const float* bnk_m  = (const float*)d_in[10];
    const float* bnk_v  = (const float*)d_in[11];
    const float* wkv_pw = (const float*)d_in[12];
    const float* w_out  = (const float*)d_in[13];
    const float* b_out  = (const float*)d_in[14];
    float* out = (float*)d_out;

    char* ws = (char*)d_ws;
    short* wq_bf  = (short*)(ws + 0);
    short* wkv_bf = (short*)(ws + 131072);
    short* wo_bf  = (short*)(ws + 393216);
    short* qd_t   = (short*)(ws + 524288);
    short* kvd_t  = (short*)(ws + 4718592);
    short* q_t    = (short*)(ws + 5242880);
    short* k_t    = (short*)(ws + 22020096);
    short* v_t    = (short*)(ws + 24117248);
    short* attn_t = (short*)(ws + 26214400);

    wconv_kernel<<<dim3(512), dim3(256), 0, stream>>>(wq_pw, wkv_pw, w_out, wq_bf, wkv_bf, wo_bf);
    dwq_kernel<<<dim3(8, 16, 4), dim3(256), 0, stream>>>(x, wq_dw, bnq_g, bnq_b, bnq_m, bnq_v, qd_t);
    dwkv_kernel<<<dim3(8, 8, 4), dim3(256), 0, stream>>>(x, wkv_dw, bnk_g, bnk_b, bnk_m, bnk_v, kvd_t);
    pwq_kernel<<<dim3(32, 4, 4), dim3(256), 0, stream>>>(wq_bf, qd_t, q_t);
    pwkv_kernel<<<dim3(4, 8, 4), dim3(256), 0, stream>>>(wkv_bf, kvd_t, k_t, v_t);
    attn_kernel<<<dim3(16, 8, 4), dim3(512), 0, stream>>>(q_t, k_t, v_t, attn_t);
    out_kernel<<<dim3(64, 1, 4), dim3(256), 0, stream>>>(wo_bf, attn_t, b_out, out);
}